// Round 12
// baseline (202.497 us; speedup 1.0000x reference)
//
#include <hip/hip_runtime.h>

#define N_NODES 16384
#define N_EDGES 262144
#define EP (N_EDGES + N_NODES)   // with self-loops
#define HID 128
#define ENC 768
#define EPSV 1e-5f

typedef unsigned short u16;
typedef unsigned char u8;
using f32x4  = __attribute__((ext_vector_type(4))) float;
using bf16x8 = __attribute__((ext_vector_type(8))) short;
using v2f    = __attribute__((ext_vector_type(2))) float;

__device__ __forceinline__ float wave_sum(float v){
  #pragma unroll
  for(int m=32;m>=1;m>>=1) v += __shfl_xor(v, m, 64);
  return v;
}
__device__ __forceinline__ float g32_sum(float v){
  #pragma unroll
  for(int m=16;m>=1;m>>=1) v += __shfl_xor(v, m, 64);
  return v;
}
__device__ __forceinline__ unsigned bf16rtne(float f){
  const unsigned u = __float_as_uint(f);
  return (u + 0x7fffu + ((u>>16)&1u)) >> 16;
}
__device__ __forceinline__ unsigned pack2(float a, float b){
  return bf16rtne(a) | (bf16rtne(b) << 16);
}
__device__ __forceinline__ float bf2f(u16 h){ return __uint_as_float(((unsigned)h) << 16); }
__device__ __forceinline__ float plo(unsigned u){ return __uint_as_float(u << 16); }
__device__ __forceinline__ float phi(unsigned u){ return __uint_as_float(u & 0xffff0000u); }
__device__ __forceinline__ u8 f2fp8(float v){
  return (u8)(__builtin_amdgcn_cvt_pk_fp8_f32(v, v, 0, false) & 0xff);
}

// 4 fp8 channels (one dword) against sg/xr registers j..j+3
#define QD(ax, j, q) { \
  const v2f f01 = __builtin_amdgcn_cvt_pk_f32_fp8(ax, false); \
  const v2f f23 = __builtin_amdgcn_cvt_pk_f32_fp8(ax, true);  \
  q = fmaf(sg[j],   __builtin_fabsf(f01.x+xr[j]),   q); \
  q = fmaf(sg[j+1], __builtin_fabsf(f01.y+xr[j+1]), q); \
  q = fmaf(sg[j+2], __builtin_fabsf(f23.x+xr[j+2]), q); \
  q = fmaf(sg[j+3], __builtin_fabsf(f23.y+xr[j+3]), q); }

// ---- merged prep: lin1 (channel-ordered pairs, +att1 dots), Wtb, hist, W2@att2 ----
#define LIN1_BLKS (N_NODES/4)            // 4096 (one wave per node)
#define WPREP_BLKS (2*ENC*HID/256)       // 768
#define HIST_BLKS (EP/256)               // 1088
#define W2A_BLKS 258                     // 128 l + 128 r + cl + cr
__global__ __launch_bounds__(256) void prep_kernel(
    const float* __restrict__ x,
    const float* __restrict__ W1l, const float* __restrict__ b1l,
    const float* __restrict__ W1r, const float* __restrict__ b1r,
    const float* __restrict__ att1,
    const float* __restrict__ W2l, const float* __restrict__ W2r,
    const float* __restrict__ b2l, const float* __restrict__ b2r,
    const float* __restrict__ att2,
    const int* __restrict__ ei,
    unsigned* __restrict__ xl1u, unsigned* __restrict__ xr1u,
    float* __restrict__ dotl1, float* __restrict__ dotr1,
    u16* __restrict__ Wtb, float* __restrict__ w2a,
    int* __restrict__ hist){
  const int bid = blockIdx.x;
  if(bid < LIN1_BLKS){
    const int lane = threadIdx.x & 63;
    const int n = bid*4 + (threadIdx.x >> 6);
    const float x0 = x[n*3], x1 = x[n*3+1], x2 = x[n*3+2];
    const int c0 = 2*lane, c1 = 2*lane + 1;     // channel-ordered pairs
    const float la = x0*W1l[c0] + x1*W1l[HID+c0] + x2*W1l[2*HID+c0] + b1l[c0];
    const float lb = x0*W1l[c1] + x1*W1l[HID+c1] + x2*W1l[2*HID+c1] + b1l[c1];
    const float ra = x0*W1r[c0] + x1*W1r[HID+c0] + x2*W1r[2*HID+c0] + b1r[c0];
    const float rb = x0*W1r[c1] + x1*W1r[HID+c1] + x2*W1r[2*HID+c1] + b1r[c1];
    const float aa = att1[c0], ab = att1[c1];
    const float dl = wave_sum(la*aa + lb*ab);
    const float dr = wave_sum(ra*aa + rb*ab);
    if(lane == 0){ dotl1[n] = 0.6f*dl; dotr1[n] = 0.6f*dr; }
    xl1u[n*64+lane] = pack2(la, lb);
    xr1u[n*64+lane] = pack2(ra, rb);
  } else if(bid < LIN1_BLKS + WPREP_BLKS){
    const int idx = (bid - LIN1_BLKS)*256 + threadIdx.x;
    const int n = idx >> 7, k = idx & 127;
    const float v = (n < ENC) ? W2l[k*ENC + n] : W2r[k*ENC + (n-ENC)];
    Wtb[idx] = (u16)bf16rtne(v);
  } else if(bid < LIN1_BLKS + WPREP_BLKS + HIST_BLKS){
    const int i = (bid - LIN1_BLKS - WPREP_BLKS)*256 + threadIdx.x;
    const int dst = (i < N_EDGES) ? ei[N_EDGES + i] : (i - N_EDGES);
    atomicAdd(&hist[dst], 1);
  } else {
    // w2a[idx]: idx<128 -> W2l@att2 row k; idx<256 -> W2r@att2; 256/257 -> att2.b2l / att2.b2r
    const int idx = bid - (LIN1_BLKS + WPREP_BLKS + HIST_BLKS);
    const float* src = (idx < 128) ? (W2l + (size_t)idx*ENC)
                     : (idx < 256) ? (W2r + (size_t)(idx-128)*ENC)
                     : (idx == 256) ? b2l : b2r;
    float partial = 0.f;
    for(int c = threadIdx.x; c < ENC; c += 256) partial += src[c]*att2[c];
    partial = wave_sum(partial);
    __shared__ float red4[4];
    if((threadIdx.x & 63) == 0) red4[threadIdx.x >> 6] = partial;
    __syncthreads();
    if(threadIdx.x == 0) w2a[idx] = red4[0]+red4[1]+red4[2]+red4[3];
  }
}

// ---- single-block exclusive scan over N=16384 (1024 thr x 16 items) ----
__global__ __launch_bounds__(1024) void scan_kernel(
    const int* __restrict__ hist, int* __restrict__ rowstart){
  __shared__ int sums[1024];
  const int t = threadIdx.x;
  const int base = t*16;
  int loc[16];
  int s = 0;
  #pragma unroll
  for(int i=0;i<16;i++){ loc[i] = s; s += hist[base+i]; }
  sums[t] = s;
  __syncthreads();
  for(int off=1; off<1024; off<<=1){
    int v = 0;
    if(t >= off) v = sums[t-off];
    __syncthreads();
    if(t >= off) sums[t] += v;
    __syncthreads();
  }
  const int prev = (t==0) ? 0 : sums[t-1];
  #pragma unroll
  for(int i=0;i<16;i++) rowstart[base+i] = prev + loc[i];
  if(t == 1023) rowstart[N_NODES] = EP;
}

// ---- CSR build: scatter src ids into dst-sorted order ----
__global__ __launch_bounds__(256) void scatter_kernel(
    const int* __restrict__ ei, const int* __restrict__ rowstart,
    int* __restrict__ cursor, int* __restrict__ ssrc){
  const int i = blockIdx.x*256 + threadIdx.x;        // exactly EP threads
  const int src = (i < N_EDGES) ? ei[i]           : (i - N_EDGES);
  const int dst = (i < N_EDGES) ? ei[N_EDGES + i] : (i - N_EDGES);
  const int pos = rowstart[dst] + atomicAdd(&cursor[dst], 1);
  ssrc[pos] = src;
}

// ---- GAT layer 1: group-of-16 per edge (8 ch/lane), 4 edges/iter across groups ----
__global__ __launch_bounds__(256) void node1_kernel(
    const unsigned* __restrict__ xl1u, const unsigned* __restrict__ xr1u,
    const float* __restrict__ att1,
    const float* __restrict__ dotl1, const float* __restrict__ dotr1,
    const float* __restrict__ bias1,
    const float* __restrict__ g1, const float* __restrict__ b1,
    const float* __restrict__ w2a,
    const int* __restrict__ rowstart, const int* __restrict__ ssrc,
    unsigned* __restrict__ h1u,
    float* __restrict__ dotl2, float* __restrict__ dotr2){
  const int lane = threadIdx.x & 63;
  const int n = blockIdx.x*4 + (threadIdx.x >> 6);
  const int g = lane >> 4, k = lane & 15;
  float xr[8], sa[8];
  {
    const uint4 u = *(const uint4*)(xr1u + n*64 + 4*k);
    xr[0]=plo(u.x); xr[1]=phi(u.x); xr[2]=plo(u.y); xr[3]=phi(u.y);
    xr[4]=plo(u.z); xr[5]=phi(u.z); xr[6]=plo(u.w); xr[7]=phi(u.w);
    const float4 a0 = *(const float4*)(att1 + 8*k);
    const float4 a1 = *(const float4*)(att1 + 8*k + 4);
    sa[0]=0.4f*a0.x; sa[1]=0.4f*a0.y; sa[2]=0.4f*a0.z; sa[3]=0.4f*a0.w;
    sa[4]=0.4f*a1.x; sa[5]=0.4f*a1.y; sa[6]=0.4f*a1.z; sa[7]=0.4f*a1.w;
  }
  const float ebase = dotr1[n];
  float acc[8] = {0,0,0,0,0,0,0,0};
  float denom = 0.f;
  const int p0 = rowstart[n], p1 = rowstart[n+1];
  for(int base = p0; base < p1; base += 4){
    const int idx = base + g;
    const bool valid = idx < p1;
    const int s = ssrc[valid ? idx : (p1-1)];
    const uint4 u = *(const uint4*)(xl1u + s*64 + 4*k);
    float a[8];
    a[0]=plo(u.x); a[1]=phi(u.x); a[2]=plo(u.y); a[3]=phi(u.y);
    a[4]=plo(u.z); a[5]=phi(u.z); a[6]=plo(u.w); a[7]=phi(u.w);
    const float dlv = dotl1[s];
    float q = 0.f;
    #pragma unroll
    for(int j=0;j<8;j++) q = fmaf(sa[j], __builtin_fabsf(a[j]+xr[j]), q);
    q += __shfl_xor(q, 1, 64);
    q += __shfl_xor(q, 2, 64);
    q += __shfl_xor(q, 4, 64);
    q += __shfl_xor(q, 8, 64);
    float w = __expf(q + dlv + ebase);
    w = valid ? w : 0.f;
    denom += w;
    #pragma unroll
    for(int j=0;j<8;j++) acc[j] = fmaf(w, a[j], acc[j]);
  }
  // combine the 4 groups (lanes with equal k)
  #pragma unroll
  for(int m=16; m<64; m<<=1){
    denom += __shfl_xor(denom, m, 64);
    #pragma unroll
    for(int j=0;j<8;j++) acc[j] += __shfl_xor(acc[j], m, 64);
  }
  const float inv = 1.f/denom;
  const float4 bb0 = *(const float4*)(bias1 + 8*k);
  const float4 bb1 = *(const float4*)(bias1 + 8*k + 4);
  float y[8];
  y[0]=acc[0]*inv+bb0.x; y[1]=acc[1]*inv+bb0.y; y[2]=acc[2]*inv+bb0.z; y[3]=acc[3]*inv+bb0.w;
  y[4]=acc[4]*inv+bb1.x; y[5]=acc[5]*inv+bb1.y; y[6]=acc[6]*inv+bb1.z; y[7]=acc[7]*inv+bb1.w;
  float ls = 0.f, lq = 0.f;
  #pragma unroll
  for(int j=0;j<8;j++){ ls += y[j]; lq += y[j]*y[j]; }
  ls = wave_sum(ls); lq = wave_sum(lq);           // 4x duplicated over groups
  const float mu  = ls * (1.f/(4*HID));
  const float var = lq * (1.f/(4*HID)) - mu*mu;
  const float r = rsqrtf(var + EPSV);
  const float4 gg0 = *(const float4*)(g1 + 8*k);
  const float4 gg1 = *(const float4*)(g1 + 8*k + 4);
  const float4 ob0 = *(const float4*)(b1 + 8*k);
  const float4 ob1 = *(const float4*)(b1 + 8*k + 4);
  const float gv[8] = {gg0.x,gg0.y,gg0.z,gg0.w,gg1.x,gg1.y,gg1.z,gg1.w};
  const float bv[8] = {ob0.x,ob0.y,ob0.z,ob0.w,ob1.x,ob1.y,ob1.z,ob1.w};
  float z[8];
  #pragma unroll
  for(int j=0;j<8;j++){
    float zz = (y[j]-mu)*r*gv[j] + bv[j];
    z[j] = zz > 0.f ? zz : expm1f(zz);            // ELU(alpha=1)
  }
  float dl2 = 0.f, dr2 = 0.f;
  #pragma unroll
  for(int j=0;j<8;j++){
    dl2 = fmaf(z[j], w2a[8*k+j], dl2);
    dr2 = fmaf(z[j], w2a[128+8*k+j], dr2);
  }
  dl2 = wave_sum(dl2); dr2 = wave_sum(dr2);       // 4x duplicated
  if(lane == 0){
    dotl2[n] = 0.6f*(0.25f*dl2 + w2a[256]);
    dotr2[n] = 0.6f*(0.25f*dr2 + w2a[257]);
  }
  if(g == 0){
    uint4 o;
    o.x = pack2(z[0], z[1]); o.y = pack2(z[2], z[3]);
    o.z = pack2(z[4], z[5]); o.w = pack2(z[6], z[7]);
    *(uint4*)(h1u + n*64 + 4*k) = o;
  }
}

// ---- MFMA GEMM: l-half -> fp8 xl8 (random src gather), r-half -> bf16 xr2u ----
#define LBM 128
#define LBN 128
__global__ __launch_bounds__(256) void mfma_lin2_kernel(
    const u16* __restrict__ h1b, const u16* __restrict__ Wtb,
    const float* __restrict__ b2l, const float* __restrict__ b2r,
    u8* __restrict__ xl8, u16* __restrict__ xr2u){
  __shared__ __align__(16) u16 Cs[LBM*128];   // 32 KB bounce, swizzled rows
  const int t = threadIdx.x;
  const int mb = blockIdx.x * LBM;
  const int nb = blockIdx.y * LBN;
  const int w = t >> 6, lane = t & 63;
  const int l15 = lane & 15, g = lane >> 4;
  const int ar0 = mb + w*32 + l15, ar1 = ar0 + 16;
  bf16x8 a0[4], a1[4];
  #pragma unroll
  for(int ks=0;ks<4;ks++){
    a0[ks] = *(const bf16x8*)(h1b + (size_t)ar0*128 + ks*32 + g*8);
    a1[ks] = *(const bf16x8*)(h1b + (size_t)ar1*128 + ks*32 + g*8);
  }
  f32x4 acc0[8], acc1[8];
  #pragma unroll
  for(int j=0;j<8;j++){ acc0[j]=(f32x4){0,0,0,0}; acc1[j]=(f32x4){0,0,0,0}; }
  #pragma unroll
  for(int j=0;j<8;j++){
    const int brn = nb + j*16 + l15;
    #pragma unroll
    for(int ks=0;ks<4;ks++){
      const bf16x8 b = *(const bf16x8*)(Wtb + (size_t)brn*128 + ks*32 + g*8);
      acc0[j] = __builtin_amdgcn_mfma_f32_16x16x32_bf16(a0[ks], b, acc0[j], 0,0,0);
      acc1[j] = __builtin_amdgcn_mfma_f32_16x16x32_bf16(a1[ks], b, acc1[j], 0,0,0);
    }
  }
  if(nb < ENC){
    // fp8 epilogue (src score table)
    u8* Cs8 = (u8*)Cs;
    float biasj[8];
    #pragma unroll
    for(int j=0;j<8;j++) biasj[j] = b2l[nb + j*16 + l15];
    #pragma unroll
    for(int j=0;j<8;j++){
      const int col = j*16 + l15;
      #pragma unroll
      for(int r4=0;r4<4;r4++){
        const int row0 = w*32 + g*4 + r4;         // C/D: col=lane&15, row=(lane>>4)*4+reg
        Cs8[row0*128 + (col ^ ((row0&7)<<4))] = f2fp8(acc0[j][r4] + biasj[j]);
        const int row1 = row0 + 16;
        Cs8[row1*128 + (col ^ ((row1&7)<<4))] = f2fp8(acc1[j][r4] + biasj[j]);
      }
    }
    __syncthreads();
    #pragma unroll
    for(int idx=t; idx<LBM*8; idx+=256){
      const int row = idx >> 3, ch = idx & 7;
      const uint4 v = *(const uint4*)(Cs8 + row*128 + ((ch*16) ^ ((row&7)<<4)));
      *(uint4*)(xl8 + (size_t)(mb+row)*ENC + nb + ch*16) = v;
    }
  } else {
    // bf16 epilogue (dst score table — loop-invariant per node in node2b)
    const float* bsrc = b2r + (nb - ENC);
    float biasj[8];
    #pragma unroll
    for(int j=0;j<8;j++) biasj[j] = bsrc[j*16 + l15];
    #pragma unroll
    for(int j=0;j<8;j++){
      const int coll = j*16 + l15;
      #pragma unroll
      for(int r4=0;r4<4;r4++){
        const int row0 = w*32 + g*4 + r4;
        *(u16*)((char*)Cs + row0*256 + ((coll*2) ^ ((row0&7)<<4))) =
            (u16)bf16rtne(acc0[j][r4] + biasj[j]);
        const int row1 = row0 + 16;
        *(u16*)((char*)Cs + row1*256 + ((coll*2) ^ ((row1&7)<<4))) =
            (u16)bf16rtne(acc1[j][r4] + biasj[j]);
      }
    }
    __syncthreads();
    u16* dst0 = xr2u + (nb - ENC);
    const int rr = t >> 4, cc = t & 15;
    #pragma unroll
    for(int it=0; it<8; ++it){
      const int row = it*16 + rr;
      const uint4 v = *(const uint4*)((const char*)Cs + row*256 + ((cc*16) ^ ((row&7)<<4)));
      *(uint4*)(dst0 + (size_t)(mb+row)*ENC + cc*8) = v;
    }
  }
}

// ---- GAT layer 2: group-of-32 per edge (24 fp8 ch/lane), 2 edges/iter,
//      unroll-2 (4 edges in flight), 1 wave per node ----
__global__ __launch_bounds__(256) void node2b_kernel(
    const u8* __restrict__ xl8, const u8* __restrict__ xr2u8,
    const float* __restrict__ att2,
    const float* __restrict__ dotl2, const float* __restrict__ dotr2,
    const unsigned* __restrict__ h1u,
    const int* __restrict__ rowstart, const int* __restrict__ ssrc,
    unsigned* __restrict__ aggb){
  const int lane = threadIdx.x & 63;
  const int n = blockIdx.x*4 + (threadIdx.x >> 6);
  const int g = lane >> 5, k = lane & 31;
  // loop-invariants: this lane's 24 channels of 0.4*att2 and xr2[n] (bf16)
  float sg[24], xr[24];
  #pragma unroll
  for(int j4=0;j4<6;j4++){
    const float4 s = *(const float4*)(att2 + 24*k + 4*j4);
    sg[4*j4]=0.4f*s.x; sg[4*j4+1]=0.4f*s.y; sg[4*j4+2]=0.4f*s.z; sg[4*j4+3]=0.4f*s.w;
  }
  {
    const u8* xrrow = xr2u8 + (size_t)n*(ENC*2) + 48*k;
    #pragma unroll
    for(int j=0;j<3;j++){
      const uint4 r = *(const uint4*)(xrrow + 16*j);
      xr[8*j]  =plo(r.x); xr[8*j+1]=phi(r.x); xr[8*j+2]=plo(r.y); xr[8*j+3]=phi(r.y);
      xr[8*j+4]=plo(r.z); xr[8*j+5]=phi(r.z); xr[8*j+6]=plo(r.w); xr[8*j+7]=phi(r.w);
    }
  }
  const float ebase = dotr2[n];
  float denom = 0.f, acc0 = 0.f, acc1 = 0.f, acc2 = 0.f, acc3 = 0.f;
  const int p0 = rowstart[n], p1 = rowstart[n+1];
  int p = p0;
  for(; p+3 < p1; p += 4){
    const int sA = ssrc[p + g];
    const int sB = ssrc[p + 2 + g];
    const u8* rA = xl8 + (size_t)sA*ENC + 24*k;
    const u8* rB = xl8 + (size_t)sB*ENC + 24*k;
    const uint2 xA0 = *(const uint2*)(rA);
    const uint2 xA1 = *(const uint2*)(rA + 8);
    const uint2 xA2 = *(const uint2*)(rA + 16);
    const uint2 xB0 = *(const uint2*)(rB);
    const uint2 xB1 = *(const uint2*)(rB + 8);
    const uint2 xB2 = *(const uint2*)(rB + 16);
    const uint2 hA = *(const uint2*)(h1u + sA*64 + 2*k);
    const uint2 hB = *(const uint2*)(h1u + sB*64 + 2*k);
    const float dlA = dotl2[sA], dlB = dotl2[sB];
    float qA = 0.f, qB = 0.f;
    QD(xA0.x, 0, qA) QD(xA0.y, 4, qA) QD(xA1.x, 8, qA)
    QD(xA1.y, 12, qA) QD(xA2.x, 16, qA) QD(xA2.y, 20, qA)
    QD(xB0.x, 0, qB) QD(xB0.y, 4, qB) QD(xB1.x, 8, qB)
    QD(xB1.y, 12, qB) QD(xB2.x, 16, qB) QD(xB2.y, 20, qB)
    #pragma unroll
    for(int m=16;m>=1;m>>=1){
      qA += __shfl_xor(qA, m, 64);
      qB += __shfl_xor(qB, m, 64);
    }
    const float wA = __expf(qA + dlA + ebase);
    const float wB = __expf(qB + dlB + ebase);
    denom += wA + wB;
    acc0 += wA*plo(hA.x) + wB*plo(hB.x);
    acc1 += wA*phi(hA.x) + wB*phi(hB.x);
    acc2 += wA*plo(hA.y) + wB*plo(hB.y);
    acc3 += wA*phi(hA.y) + wB*phi(hB.y);
  }
  for(; p < p1; p += 2){
    const int idx = p + g;
    const bool valid = idx < p1;
    const int s = ssrc[valid ? idx : p];
    const u8* r = xl8 + (size_t)s*ENC + 24*k;
    const uint2 x0 = *(const uint2*)(r);
    const uint2 x1 = *(const uint2*)(r + 8);
    const uint2 x2 = *(const uint2*)(r + 16);
    const uint2 h = *(const uint2*)(h1u + s*64 + 2*k);
    const float dl = dotl2[s];
    float q = 0.f;
    QD(x0.x, 0, q) QD(x0.y, 4, q) QD(x1.x, 8, q)
    QD(x1.y, 12, q) QD(x2.x, 16, q) QD(x2.y, 20, q)
    q = g32_sum(q);
    float w = __expf(q + dl + ebase);
    w = valid ? w : 0.f;
    denom += w;
    acc0 += w*plo(h.x); acc1 += w*phi(h.x);
    acc2 += w*plo(h.y); acc3 += w*phi(h.y);
  }
  // combine the two 32-lane groups
  denom += __shfl_xor(denom, 32, 64);
  acc0 += __shfl_xor(acc0, 32, 64);
  acc1 += __shfl_xor(acc1, 32, 64);
  acc2 += __shfl_xor(acc2, 32, 64);
  acc3 += __shfl_xor(acc3, 32, 64);
  if(g == 0){
    const float inv = 1.f/denom;
    aggb[n*64 + 2*k]     = pack2(acc0*inv, acc1*inv);   // channels 4k,4k+1
    aggb[n*64 + 2*k + 1] = pack2(acc2*inv, acc3*inv);   // channels 4k+2,4k+3
  }
}

// ---- final fused: out = LN( aggb@W2l + b2l + bias2 + x@Wfc + bfc ) ----
#define YSTR 770
__global__ __launch_bounds__(256) void gemm3_mfma_kernel(
    const u16* __restrict__ aggb, const u16* __restrict__ Wtb,
    const float* __restrict__ b2l, const float* __restrict__ bias2,
    const float* __restrict__ x, const float* __restrict__ Wfc,
    const float* __restrict__ bfc,
    const float* __restrict__ gn, const float* __restrict__ bn,
    float* __restrict__ out){
  __shared__ u16 Ys[64*YSTR];
  __shared__ float cbs[ENC];
  __shared__ float wfs[3][ENC];
  __shared__ float mus[64], rss[64];
  const int t = threadIdx.x;
  const int mb = blockIdx.x * 64;
  for(int c=t; c<ENC; c+=256){
    cbs[c] = b2l[c] + bias2[c] + bfc[c];
    wfs[0][c] = Wfc[c]; wfs[1][c] = Wfc[ENC+c]; wfs[2][c] = Wfc[2*ENC+c];
  }
  const int w = t >> 6, lane = t & 63;
  const int l15 = lane & 15, g = lane >> 4;
  const int ar = mb + w*16 + l15;
  bf16x8 a[4];
  #pragma unroll
  for(int ks=0;ks<4;ks++)
    a[ks] = *(const bf16x8*)(aggb + (size_t)ar*128 + ks*32 + g*8);
  float xv0[4], xv1[4], xv2[4];
  #pragma unroll
  for(int r4=0;r4<4;r4++){
    const int rrow = mb + w*16 + g*4 + r4;
    xv0[r4] = x[rrow*3]; xv1[r4] = x[rrow*3+1]; xv2[r4] = x[rrow*3+2];
  }
  float rs[4] = {0,0,0,0}, rq[4] = {0,0,0,0};
  __syncthreads();
  #pragma unroll
  for(int sub=0; sub<6; ++sub){
    const int nb = sub*128;
    f32x4 acc[8];
    #pragma unroll
    for(int j=0;j<8;j++) acc[j]=(f32x4){0,0,0,0};
    #pragma unroll
    for(int j=0;j<8;j++){
      const int brn = nb + j*16 + l15;
      #pragma unroll
      for(int ks=0;ks<4;ks++){
        const bf16x8 b = *(const bf16x8*)(Wtb + (size_t)brn*128 + ks*32 + g*8);
        acc[j] = __builtin_amdgcn_mfma_f32_16x16x32_bf16(a[ks], b, acc[j], 0,0,0);
      }
    }
    #pragma unroll
    for(int j=0;j<8;j++){
      const int col = nb + j*16 + l15;
      const float cb = cbs[col];
      const float w0 = wfs[0][col], w1 = wfs[1][col], w2 = wfs[2][col];
      #pragma unroll
      for(int r4=0;r4<4;r4++){
        const int lrow = w*16 + g*4 + r4;
        const float y = acc[j][r4] + cb + xv0[r4]*w0 + xv1[r4]*w1 + xv2[r4]*w2;
        rs[r4] += y; rq[r4] += y*y;
        Ys[lrow*YSTR + col] = (u16)bf16rtne(y);
      }
    }
  }
  #pragma unroll
  for(int m=8;m>=1;m>>=1){
    #pragma unroll
    for(int r4=0;r4<4;r4++){
      rs[r4] += __shfl_xor(rs[r4], m, 64);
      rq[r4] += __shfl_xor(rq[r4], m, 64);
    }
  }
  if(l15 == 0){
    #pragma unroll
    for(int r4=0;r4<4;r4++){
      const int lrow = w*16 + g*4 + r4;
      const float mu = rs[r4] * (1.f/ENC);
      const float var = rq[r4] * (1.f/ENC) - mu*mu;
      mus[lrow] = mu;
      rss[lrow] = rsqrtf(var + EPSV);
    }
  }
  __syncthreads();
  float gv[12], bv[12];
  #pragma unroll
  for(int j2=0;j2<12;j2++){ gv[j2] = gn[lane + j2*64]; bv[j2] = bn[lane + j2*64]; }
  for(int r=0; r<16; ++r){
    const int lrow = w*16 + r;
    const float mu = mus[lrow], rstd = rss[lrow];
    float* orow = out + (size_t)(mb+lrow)*ENC;
    #pragma unroll
    for(int j2=0;j2<12;j2++){
      const float y = bf2f(Ys[lrow*YSTR + lane + j2*64]);
      orow[lane + j2*64] = (y - mu)*rstd*gv[j2] + bv[j2];
    }
  }
}

extern "C" void kernel_launch(void* const* d_in, const int* in_sizes, int n_in,
                              void* d_out, int out_size, void* d_ws, size_t ws_size,
                              hipStream_t stream) {
  const float* x    = (const float*)d_in[0];
  const int*   ei   = (const int*)  d_in[1];
  const float* Wfc  = (const float*)d_in[2];
  const float* bfc  = (const float*)d_in[3];
  const float* W1l  = (const float*)d_in[4];
  const float* b1l  = (const float*)d_in[5];
  const float* W1r  = (const float*)d_in[6];
  const float* b1r  = (const float*)d_in[7];
  const float* att1 = (const float*)d_in[8];
  const float* bias1= (const float*)d_in[9];
  const float* g1   = (const float*)d_in[10];
  const float* bb1  = (const float*)d_in[11];
  const float* W2l  = (const float*)d_in[12];
  const float* b2l  = (const float*)d_in[13];
  const float* W2r  = (const float*)d_in[14];
  const float* b2r  = (const float*)d_in[15];
  const float* att2 = (const float*)d_in[16];
  const float* bias2= (const float*)d_in[17];
  const float* gn   = (const float*)d_in[18];
  const float* bn   = (const float*)d_in[19];
  float* out = (float*)d_out;

  char* w = (char*)d_ws;
  auto alloc = [&](size_t bytes){ void* p = (void*)w; w += (bytes + 255) & ~(size_t)255; return p; };
  int*      hist     = (int*)     alloc((size_t)N_NODES*4);   // contiguous with cursor
  int*      cursor   = (int*)     alloc((size_t)N_NODES*4);
  int*      rowstart = (int*)     alloc((size_t)(N_NODES+1)*4);
  int*      ssrc     = (int*)     alloc((size_t)EP*4);
  unsigned* xl1u     = (unsigned*)alloc((size_t)N_NODES*64*4);
  unsigned* xr1u     = (unsigned*)alloc((size_t)N_NODES*64*4);
  float*    dotl1    = (float*)   alloc((size_t)N_NODES*4);
  float*    dotr1    = (float*)   alloc((size_t)N_NODES*4);
  float*    dotl2    = (float*)   alloc((size_t)N_NODES*4);
  float*    dotr2    = (float*)   alloc((size_t)N_NODES*4);
  unsigned* h1u      = (unsigned*)alloc((size_t)N_NODES*64*4);
  unsigned* aggb     = (unsigned*)alloc((size_t)N_NODES*64*4);
  u8*       xl8      = (u8*)      alloc((size_t)N_NODES*ENC);
  u16*      xr2u     = (u16*)     alloc((size_t)N_NODES*ENC*2);
  u16*      Wtb      = (u16*)     alloc((size_t)2*ENC*HID*2);
  float*    w2a      = (float*)   alloc((size_t)W2A_BLKS*4);

  hipMemsetAsync(hist, 0, (size_t)N_NODES*8, stream);   // hist + cursor

  prep_kernel<<<LIN1_BLKS+WPREP_BLKS+HIST_BLKS+W2A_BLKS, 256, 0, stream>>>(
      x, W1l, b1l, W1r, b1r, att1, W2l, W2r, b2l, b2r, att2, ei,
      xl1u, xr1u, dotl1, dotr1, Wtb, w2a, hist);
  scan_kernel<<<1, 1024, 0, stream>>>(hist, rowstart);
  scatter_kernel<<<EP/256, 256, 0, stream>>>(ei, rowstart, cursor, ssrc);
  node1_kernel<<<N_NODES/4, 256, 0, stream>>>(xl1u, xr1u, att1, dotl1, dotr1,
                                              bias1, g1, bb1, w2a,
                                              rowstart, ssrc, h1u, dotl2, dotr2);
  mfma_lin2_kernel<<<dim3(N_NODES/LBM, 2*ENC/LBN), 256, 0, stream>>>(
      (const u16*)h1u, Wtb, b2l, b2r, xl8, xr2u);
  node2b_kernel<<<N_NODES/4, 256, 0, stream>>>(xl8, (const u8*)xr2u, att2,
                                               dotl2, dotr2, h1u,
                                               rowstart, ssrc, aggb);
  gemm3_mfma_kernel<<<N_NODES/64, 256, 0, stream>>>((const u16*)aggb, Wtb, b2l, bias2,
                                                    x, Wfc, bfc, gn, bn, out);
}

// Round 13
// 188.258 us; speedup vs baseline: 1.0756x; 1.0756x over previous
//
#include <hip/hip_runtime.h>

#define N_NODES 16384
#define N_EDGES 262144
#define EP (N_EDGES + N_NODES)   // with self-loops
#define HID 128
#define ENC 768
#define EPSV 1e-5f

typedef unsigned short u16;
typedef unsigned char u8;
using f32x4  = __attribute__((ext_vector_type(4))) float;
using bf16x8 = __attribute__((ext_vector_type(8))) short;
using v2f    = __attribute__((ext_vector_type(2))) float;

__device__ __forceinline__ float wave_sum(float v){
  #pragma unroll
  for(int m=32;m>=1;m>>=1) v += __shfl_xor(v, m, 64);
  return v;
}
__device__ __forceinline__ unsigned bf16rtne(float f){
  const unsigned u = __float_as_uint(f);
  return (u + 0x7fffu + ((u>>16)&1u)) >> 16;
}
__device__ __forceinline__ unsigned pack2(float a, float b){
  return bf16rtne(a) | (bf16rtne(b) << 16);
}
__device__ __forceinline__ float bf2f(u16 h){ return __uint_as_float(((unsigned)h) << 16); }
__device__ __forceinline__ float plo(unsigned u){ return __uint_as_float(u << 16); }
__device__ __forceinline__ float phi(unsigned u){ return __uint_as_float(u & 0xffff0000u); }
__device__ __forceinline__ u8 f2fp8(float v){
  return (u8)(__builtin_amdgcn_cvt_pk_fp8_f32(v, v, 0, false) & 0xff);
}

// 4 fp8 channels (one dword) against sg/xr registers j..j+3
#define QD(ax, j, q) { \
  const v2f f01 = __builtin_amdgcn_cvt_pk_f32_fp8(ax, false); \
  const v2f f23 = __builtin_amdgcn_cvt_pk_f32_fp8(ax, true);  \
  q = fmaf(sg[j],   __builtin_fabsf(f01.x+xr[j]),   q); \
  q = fmaf(sg[j+1], __builtin_fabsf(f01.y+xr[j+1]), q); \
  q = fmaf(sg[j+2], __builtin_fabsf(f23.x+xr[j+2]), q); \
  q = fmaf(sg[j+3], __builtin_fabsf(f23.y+xr[j+3]), q); }

// ---- merged prep: lin1 (channel-ordered pairs, +att1 dots), Wtb, hist, W2@att2 ----
#define LIN1_BLKS (N_NODES/4)            // 4096 (one wave per node)
#define WPREP_BLKS (2*ENC*HID/256)       // 768
#define HIST_BLKS (EP/256)               // 1088
#define W2A_BLKS 258                     // 128 l + 128 r + cl + cr
__global__ __launch_bounds__(256) void prep_kernel(
    const float* __restrict__ x,
    const float* __restrict__ W1l, const float* __restrict__ b1l,
    const float* __restrict__ W1r, const float* __restrict__ b1r,
    const float* __restrict__ att1,
    const float* __restrict__ W2l, const float* __restrict__ W2r,
    const float* __restrict__ b2l, const float* __restrict__ b2r,
    const float* __restrict__ att2,
    const int* __restrict__ ei,
    unsigned* __restrict__ xl1u, unsigned* __restrict__ xr1u,
    float* __restrict__ dotl1, float* __restrict__ dotr1,
    u16* __restrict__ Wtb, float* __restrict__ w2a,
    int* __restrict__ hist){
  const int bid = blockIdx.x;
  if(bid < LIN1_BLKS){
    const int lane = threadIdx.x & 63;
    const int n = bid*4 + (threadIdx.x >> 6);
    const float x0 = x[n*3], x1 = x[n*3+1], x2 = x[n*3+2];
    const int c0 = 2*lane, c1 = 2*lane + 1;     // channel-ordered pairs
    const float la = x0*W1l[c0] + x1*W1l[HID+c0] + x2*W1l[2*HID+c0] + b1l[c0];
    const float lb = x0*W1l[c1] + x1*W1l[HID+c1] + x2*W1l[2*HID+c1] + b1l[c1];
    const float ra = x0*W1r[c0] + x1*W1r[HID+c0] + x2*W1r[2*HID+c0] + b1r[c0];
    const float rb = x0*W1r[c1] + x1*W1r[HID+c1] + x2*W1r[2*HID+c1] + b1r[c1];
    const float aa = att1[c0], ab = att1[c1];
    const float dl = wave_sum(la*aa + lb*ab);
    const float dr = wave_sum(ra*aa + rb*ab);
    if(lane == 0){ dotl1[n] = 0.6f*dl; dotr1[n] = 0.6f*dr; }
    xl1u[n*64+lane] = pack2(la, lb);
    xr1u[n*64+lane] = pack2(ra, rb);
  } else if(bid < LIN1_BLKS + WPREP_BLKS){
    const int idx = (bid - LIN1_BLKS)*256 + threadIdx.x;
    const int n = idx >> 7, k = idx & 127;
    const float v = (n < ENC) ? W2l[k*ENC + n] : W2r[k*ENC + (n-ENC)];
    Wtb[idx] = (u16)bf16rtne(v);
  } else if(bid < LIN1_BLKS + WPREP_BLKS + HIST_BLKS){
    const int i = (bid - LIN1_BLKS - WPREP_BLKS)*256 + threadIdx.x;
    const int dst = (i < N_EDGES) ? ei[N_EDGES + i] : (i - N_EDGES);
    atomicAdd(&hist[dst], 1);
  } else {
    // w2a[idx]: idx<128 -> W2l@att2 row k; idx<256 -> W2r@att2; 256/257 -> att2.b2l / att2.b2r
    const int idx = bid - (LIN1_BLKS + WPREP_BLKS + HIST_BLKS);
    const float* src = (idx < 128) ? (W2l + (size_t)idx*ENC)
                     : (idx < 256) ? (W2r + (size_t)(idx-128)*ENC)
                     : (idx == 256) ? b2l : b2r;
    float partial = 0.f;
    for(int c = threadIdx.x; c < ENC; c += 256) partial += src[c]*att2[c];
    partial = wave_sum(partial);
    __shared__ float red4[4];
    if((threadIdx.x & 63) == 0) red4[threadIdx.x >> 6] = partial;
    __syncthreads();
    if(threadIdx.x == 0) w2a[idx] = red4[0]+red4[1]+red4[2]+red4[3];
  }
}

// ---- single-block exclusive scan over N=16384 (1024 thr x 16 items) ----
__global__ __launch_bounds__(1024) void scan_kernel(
    const int* __restrict__ hist, int* __restrict__ rowstart){
  __shared__ int sums[1024];
  const int t = threadIdx.x;
  const int base = t*16;
  int loc[16];
  int s = 0;
  #pragma unroll
  for(int i=0;i<16;i++){ loc[i] = s; s += hist[base+i]; }
  sums[t] = s;
  __syncthreads();
  for(int off=1; off<1024; off<<=1){
    int v = 0;
    if(t >= off) v = sums[t-off];
    __syncthreads();
    if(t >= off) sums[t] += v;
    __syncthreads();
  }
  const int prev = (t==0) ? 0 : sums[t-1];
  #pragma unroll
  for(int i=0;i<16;i++) rowstart[base+i] = prev + loc[i];
  if(t == 1023) rowstart[N_NODES] = EP;
}

// ---- CSR build: scatter src ids into dst-sorted order ----
__global__ __launch_bounds__(256) void scatter_kernel(
    const int* __restrict__ ei, const int* __restrict__ rowstart,
    int* __restrict__ cursor, int* __restrict__ ssrc){
  const int i = blockIdx.x*256 + threadIdx.x;        // exactly EP threads
  const int src = (i < N_EDGES) ? ei[i]           : (i - N_EDGES);
  const int dst = (i < N_EDGES) ? ei[N_EDGES + i] : (i - N_EDGES);
  const int pos = rowstart[dst] + atomicAdd(&cursor[dst], 1);
  ssrc[pos] = src;
}

// ---- GAT layer 1: group-of-16 per edge (8 ch/lane), 4 edges/iter across groups ----
__global__ __launch_bounds__(256) void node1_kernel(
    const unsigned* __restrict__ xl1u, const unsigned* __restrict__ xr1u,
    const float* __restrict__ att1,
    const float* __restrict__ dotl1, const float* __restrict__ dotr1,
    const float* __restrict__ bias1,
    const float* __restrict__ g1, const float* __restrict__ b1,
    const float* __restrict__ w2a,
    const int* __restrict__ rowstart, const int* __restrict__ ssrc,
    unsigned* __restrict__ h1u,
    float* __restrict__ dotl2, float* __restrict__ dotr2){
  const int lane = threadIdx.x & 63;
  const int n = blockIdx.x*4 + (threadIdx.x >> 6);
  const int g = lane >> 4, k = lane & 15;
  float xr[8], sa[8];
  {
    const uint4 u = *(const uint4*)(xr1u + n*64 + 4*k);
    xr[0]=plo(u.x); xr[1]=phi(u.x); xr[2]=plo(u.y); xr[3]=phi(u.y);
    xr[4]=plo(u.z); xr[5]=phi(u.z); xr[6]=plo(u.w); xr[7]=phi(u.w);
    const float4 a0 = *(const float4*)(att1 + 8*k);
    const float4 a1 = *(const float4*)(att1 + 8*k + 4);
    sa[0]=0.4f*a0.x; sa[1]=0.4f*a0.y; sa[2]=0.4f*a0.z; sa[3]=0.4f*a0.w;
    sa[4]=0.4f*a1.x; sa[5]=0.4f*a1.y; sa[6]=0.4f*a1.z; sa[7]=0.4f*a1.w;
  }
  const float ebase = dotr1[n];
  float acc[8] = {0,0,0,0,0,0,0,0};
  float denom = 0.f;
  const int p0 = rowstart[n], p1 = rowstart[n+1];
  for(int base = p0; base < p1; base += 4){
    const int idx = base + g;
    const bool valid = idx < p1;
    const int s = ssrc[valid ? idx : (p1-1)];
    const uint4 u = *(const uint4*)(xl1u + s*64 + 4*k);
    float a[8];
    a[0]=plo(u.x); a[1]=phi(u.x); a[2]=plo(u.y); a[3]=phi(u.y);
    a[4]=plo(u.z); a[5]=phi(u.z); a[6]=plo(u.w); a[7]=phi(u.w);
    const float dlv = dotl1[s];
    float q = 0.f;
    #pragma unroll
    for(int j=0;j<8;j++) q = fmaf(sa[j], __builtin_fabsf(a[j]+xr[j]), q);
    q += __shfl_xor(q, 1, 64);
    q += __shfl_xor(q, 2, 64);
    q += __shfl_xor(q, 4, 64);
    q += __shfl_xor(q, 8, 64);
    float w = __expf(q + dlv + ebase);
    w = valid ? w : 0.f;
    denom += w;
    #pragma unroll
    for(int j=0;j<8;j++) acc[j] = fmaf(w, a[j], acc[j]);
  }
  // combine the 4 groups (lanes with equal k)
  #pragma unroll
  for(int m=16; m<64; m<<=1){
    denom += __shfl_xor(denom, m, 64);
    #pragma unroll
    for(int j=0;j<8;j++) acc[j] += __shfl_xor(acc[j], m, 64);
  }
  const float inv = 1.f/denom;
  const float4 bb0 = *(const float4*)(bias1 + 8*k);
  const float4 bb1 = *(const float4*)(bias1 + 8*k + 4);
  float y[8];
  y[0]=acc[0]*inv+bb0.x; y[1]=acc[1]*inv+bb0.y; y[2]=acc[2]*inv+bb0.z; y[3]=acc[3]*inv+bb0.w;
  y[4]=acc[4]*inv+bb1.x; y[5]=acc[5]*inv+bb1.y; y[6]=acc[6]*inv+bb1.z; y[7]=acc[7]*inv+bb1.w;
  float ls = 0.f, lq = 0.f;
  #pragma unroll
  for(int j=0;j<8;j++){ ls += y[j]; lq += y[j]*y[j]; }
  ls = wave_sum(ls); lq = wave_sum(lq);           // 4x duplicated over groups
  const float mu  = ls * (1.f/(4*HID));
  const float var = lq * (1.f/(4*HID)) - mu*mu;
  const float r = rsqrtf(var + EPSV);
  const float4 gg0 = *(const float4*)(g1 + 8*k);
  const float4 gg1 = *(const float4*)(g1 + 8*k + 4);
  const float4 ob0 = *(const float4*)(b1 + 8*k);
  const float4 ob1 = *(const float4*)(b1 + 8*k + 4);
  const float gv[8] = {gg0.x,gg0.y,gg0.z,gg0.w,gg1.x,gg1.y,gg1.z,gg1.w};
  const float bv[8] = {ob0.x,ob0.y,ob0.z,ob0.w,ob1.x,ob1.y,ob1.z,ob1.w};
  float z[8];
  #pragma unroll
  for(int j=0;j<8;j++){
    float zz = (y[j]-mu)*r*gv[j] + bv[j];
    z[j] = zz > 0.f ? zz : expm1f(zz);            // ELU(alpha=1)
  }
  float dl2 = 0.f, dr2 = 0.f;
  #pragma unroll
  for(int j=0;j<8;j++){
    dl2 = fmaf(z[j], w2a[8*k+j], dl2);
    dr2 = fmaf(z[j], w2a[128+8*k+j], dr2);
  }
  dl2 = wave_sum(dl2); dr2 = wave_sum(dr2);       // 4x duplicated
  if(lane == 0){
    dotl2[n] = 0.6f*(0.25f*dl2 + w2a[256]);
    dotr2[n] = 0.6f*(0.25f*dr2 + w2a[257]);
  }
  if(g == 0){
    uint4 o;
    o.x = pack2(z[0], z[1]); o.y = pack2(z[2], z[3]);
    o.z = pack2(z[4], z[5]); o.w = pack2(z[6], z[7]);
    *(uint4*)(h1u + n*64 + 4*k) = o;
  }
}

// ---- MFMA GEMM: l-half -> fp8 xl8 (random src gather), r-half -> bf16 xr2u ----
#define LBM 128
#define LBN 128
__global__ __launch_bounds__(256) void mfma_lin2_kernel(
    const u16* __restrict__ h1b, const u16* __restrict__ Wtb,
    const float* __restrict__ b2l, const float* __restrict__ b2r,
    u8* __restrict__ xl8, u16* __restrict__ xr2u){
  __shared__ __align__(16) u16 Cs[LBM*128];   // 32 KB bounce, swizzled rows
  const int t = threadIdx.x;
  const int mb = blockIdx.x * LBM;
  const int nb = blockIdx.y * LBN;
  const int w = t >> 6, lane = t & 63;
  const int l15 = lane & 15, g = lane >> 4;
  const int ar0 = mb + w*32 + l15, ar1 = ar0 + 16;
  bf16x8 a0[4], a1[4];
  #pragma unroll
  for(int ks=0;ks<4;ks++){
    a0[ks] = *(const bf16x8*)(h1b + (size_t)ar0*128 + ks*32 + g*8);
    a1[ks] = *(const bf16x8*)(h1b + (size_t)ar1*128 + ks*32 + g*8);
  }
  f32x4 acc0[8], acc1[8];
  #pragma unroll
  for(int j=0;j<8;j++){ acc0[j]=(f32x4){0,0,0,0}; acc1[j]=(f32x4){0,0,0,0}; }
  #pragma unroll
  for(int j=0;j<8;j++){
    const int brn = nb + j*16 + l15;
    #pragma unroll
    for(int ks=0;ks<4;ks++){
      const bf16x8 b = *(const bf16x8*)(Wtb + (size_t)brn*128 + ks*32 + g*8);
      acc0[j] = __builtin_amdgcn_mfma_f32_16x16x32_bf16(a0[ks], b, acc0[j], 0,0,0);
      acc1[j] = __builtin_amdgcn_mfma_f32_16x16x32_bf16(a1[ks], b, acc1[j], 0,0,0);
    }
  }
  if(nb < ENC){
    // fp8 epilogue (src score table)
    u8* Cs8 = (u8*)Cs;
    float biasj[8];
    #pragma unroll
    for(int j=0;j<8;j++) biasj[j] = b2l[nb + j*16 + l15];
    #pragma unroll
    for(int j=0;j<8;j++){
      const int col = j*16 + l15;
      #pragma unroll
      for(int r4=0;r4<4;r4++){
        const int row0 = w*32 + g*4 + r4;         // C/D: col=lane&15, row=(lane>>4)*4+reg
        Cs8[row0*128 + (col ^ ((row0&7)<<4))] = f2fp8(acc0[j][r4] + biasj[j]);
        const int row1 = row0 + 16;
        Cs8[row1*128 + (col ^ ((row1&7)<<4))] = f2fp8(acc1[j][r4] + biasj[j]);
      }
    }
    __syncthreads();
    #pragma unroll
    for(int idx=t; idx<LBM*8; idx+=256){
      const int row = idx >> 3, ch = idx & 7;
      const uint4 v = *(const uint4*)(Cs8 + row*128 + ((ch*16) ^ ((row&7)<<4)));
      *(uint4*)(xl8 + (size_t)(mb+row)*ENC + nb + ch*16) = v;
    }
  } else {
    // bf16 epilogue (dst score table — loop-invariant per node in node2b)
    const float* bsrc = b2r + (nb - ENC);
    float biasj[8];
    #pragma unroll
    for(int j=0;j<8;j++) biasj[j] = bsrc[j*16 + l15];
    #pragma unroll
    for(int j=0;j<8;j++){
      const int coll = j*16 + l15;
      #pragma unroll
      for(int r4=0;r4<4;r4++){
        const int row0 = w*32 + g*4 + r4;
        *(u16*)((char*)Cs + row0*256 + ((coll*2) ^ ((row0&7)<<4))) =
            (u16)bf16rtne(acc0[j][r4] + biasj[j]);
        const int row1 = row0 + 16;
        *(u16*)((char*)Cs + row1*256 + ((coll*2) ^ ((row1&7)<<4))) =
            (u16)bf16rtne(acc1[j][r4] + biasj[j]);
      }
    }
    __syncthreads();
    u16* dst0 = xr2u + (nb - ENC);
    const int rr = t >> 4, cc = t & 15;
    #pragma unroll
    for(int it=0; it<8; ++it){
      const int row = it*16 + rr;
      const uint4 v = *(const uint4*)((const char*)Cs + row*256 + ((cc*16) ^ ((row&7)<<4)));
      *(uint4*)(dst0 + (size_t)(mb+row)*ENC + cc*8) = v;
    }
  }
}

// ---- GAT layer 2: channel-parallel (12 fp8 ch/lane, uint3 row read),
//      8-edge unroll for deep MLP; 1 wave per node; canonical h1u ----
__global__ __launch_bounds__(256) void node2b_kernel(
    const u8* __restrict__ xl8, const u8* __restrict__ xr2u8,
    const float* __restrict__ att2,
    const float* __restrict__ dotl2, const float* __restrict__ dotr2,
    const unsigned* __restrict__ h1u,
    const int* __restrict__ rowstart, const int* __restrict__ ssrc,
    unsigned* __restrict__ aggb){
  const int lane = threadIdx.x & 63;
  const int n = blockIdx.x*4 + (threadIdx.x >> 6);
  // loop-invariant: this lane's 12 channels of 0.4*att2 and xr2[n]
  float sg[12], xr[12];
  {
    const float4* A4 = (const float4*)(att2 + lane*12);   // 48B stride, 16-aligned
    const float4 s0 = A4[0], s1 = A4[1], s2 = A4[2];
    sg[0]=0.4f*s0.x; sg[1]=0.4f*s0.y; sg[2]=0.4f*s0.z; sg[3]=0.4f*s0.w;
    sg[4]=0.4f*s1.x; sg[5]=0.4f*s1.y; sg[6]=0.4f*s1.z; sg[7]=0.4f*s1.w;
    sg[8]=0.4f*s2.x; sg[9]=0.4f*s2.y; sg[10]=0.4f*s2.z; sg[11]=0.4f*s2.w;
    const u8* xrrow = xr2u8 + (size_t)n*(ENC*2) + lane*24;
    const uint2 r0 = *(const uint2*)(xrrow);
    const uint2 r1 = *(const uint2*)(xrrow + 8);
    const uint2 r2 = *(const uint2*)(xrrow + 16);
    xr[0]=plo(r0.x); xr[1]=phi(r0.x); xr[2]=plo(r0.y); xr[3]=phi(r0.y);
    xr[4]=plo(r1.x); xr[5]=phi(r1.x); xr[6]=plo(r1.y); xr[7]=phi(r1.y);
    xr[8]=plo(r2.x); xr[9]=phi(r2.x); xr[10]=plo(r2.y); xr[11]=phi(r2.y);
  }
  const float ebase = dotr2[n];
  float denom = 0.f, acc0 = 0.f, acc1 = 0.f;
  int p = rowstart[n];
  const int p1 = rowstart[n+1];
  for(; p+7 < p1; p += 8){
    int s[8];
    #pragma unroll
    for(int e=0;e<8;e++) s[e] = ssrc[p+e];
    uint3 a[8]; unsigned h[8]; float dl[8];
    #pragma unroll
    for(int e=0;e<8;e++){
      a[e]  = *(const uint3*)(xl8 + (size_t)s[e]*ENC + lane*12);
      h[e]  = h1u[s[e]*64 + lane];
      dl[e] = dotl2[s[e]];
    }
    float q[8];
    #pragma unroll
    for(int e=0;e<8;e++){
      q[e] = 0.f;
      QD(a[e].x, 0, q[e]) QD(a[e].y, 4, q[e]) QD(a[e].z, 8, q[e])
    }
    #pragma unroll
    for(int m=32;m>=1;m>>=1){
      #pragma unroll
      for(int e=0;e<8;e++) q[e] += __shfl_xor(q[e], m, 64);
    }
    #pragma unroll
    for(int e=0;e<8;e++){
      const float w = __expf(q[e] + dl[e] + ebase);
      denom += w;
      acc0 += w*plo(h[e]);
      acc1 += w*phi(h[e]);
    }
  }
  for(; p < p1; ++p){
    const int s0 = ssrc[p];
    const uint3 a0 = *(const uint3*)(xl8 + (size_t)s0*ENC + lane*12);
    float q0 = 0.f;
    QD(a0.x, 0, q0) QD(a0.y, 4, q0) QD(a0.z, 8, q0)
    const unsigned h0 = h1u[s0*64 + lane];
    const float w0 = __expf(wave_sum(q0) + dotl2[s0] + ebase);
    denom += w0; acc0 += w0*plo(h0); acc1 += w0*phi(h0);
  }
  const float inv = 1.f/denom;
  aggb[n*64 + lane] = pack2(acc0*inv, acc1*inv);    // channels 2lane, 2lane+1
}

// ---- final fused: out = LN( aggb@W2l + b2l + bias2 + x@Wfc + bfc ) ----
#define YSTR 770
__global__ __launch_bounds__(256) void gemm3_mfma_kernel(
    const u16* __restrict__ aggb, const u16* __restrict__ Wtb,
    const float* __restrict__ b2l, const float* __restrict__ bias2,
    const float* __restrict__ x, const float* __restrict__ Wfc,
    const float* __restrict__ bfc,
    const float* __restrict__ gn, const float* __restrict__ bn,
    float* __restrict__ out){
  __shared__ u16 Ys[64*YSTR];
  __shared__ float cbs[ENC];
  __shared__ float wfs[3][ENC];
  __shared__ float mus[64], rss[64];
  const int t = threadIdx.x;
  const int mb = blockIdx.x * 64;
  for(int c=t; c<ENC; c+=256){
    cbs[c] = b2l[c] + bias2[c] + bfc[c];
    wfs[0][c] = Wfc[c]; wfs[1][c] = Wfc[ENC+c]; wfs[2][c] = Wfc[2*ENC+c];
  }
  const int w = t >> 6, lane = t & 63;
  const int l15 = lane & 15, g = lane >> 4;
  const int ar = mb + w*16 + l15;
  bf16x8 a[4];
  #pragma unroll
  for(int ks=0;ks<4;ks++)
    a[ks] = *(const bf16x8*)(aggb + (size_t)ar*128 + ks*32 + g*8);
  float xv0[4], xv1[4], xv2[4];
  #pragma unroll
  for(int r4=0;r4<4;r4++){
    const int rrow = mb + w*16 + g*4 + r4;
    xv0[r4] = x[rrow*3]; xv1[r4] = x[rrow*3+1]; xv2[r4] = x[rrow*3+2];
  }
  float rs[4] = {0,0,0,0}, rq[4] = {0,0,0,0};
  __syncthreads();
  #pragma unroll
  for(int sub=0; sub<6; ++sub){
    const int nb = sub*128;
    f32x4 acc[8];
    #pragma unroll
    for(int j=0;j<8;j++) acc[j]=(f32x4){0,0,0,0};
    #pragma unroll
    for(int j=0;j<8;j++){
      const int brn = nb + j*16 + l15;
      #pragma unroll
      for(int ks=0;ks<4;ks++){
        const bf16x8 b = *(const bf16x8*)(Wtb + (size_t)brn*128 + ks*32 + g*8);
        acc[j] = __builtin_amdgcn_mfma_f32_16x16x32_bf16(a[ks], b, acc[j], 0,0,0);
      }
    }
    #pragma unroll
    for(int j=0;j<8;j++){
      const int col = nb + j*16 + l15;
      const float cb = cbs[col];
      const float w0 = wfs[0][col], w1 = wfs[1][col], w2 = wfs[2][col];
      #pragma unroll
      for(int r4=0;r4<4;r4++){
        const int lrow = w*16 + g*4 + r4;
        const float y = acc[j][r4] + cb + xv0[r4]*w0 + xv1[r4]*w1 + xv2[r4]*w2;
        rs[r4] += y; rq[r4] += y*y;
        Ys[lrow*YSTR + col] = (u16)bf16rtne(y);
      }
    }
  }
  #pragma unroll
  for(int m=8;m>=1;m>>=1){
    #pragma unroll
    for(int r4=0;r4<4;r4++){
      rs[r4] += __shfl_xor(rs[r4], m, 64);
      rq[r4] += __shfl_xor(rq[r4], m, 64);
    }
  }
  if(l15 == 0){
    #pragma unroll
    for(int r4=0;r4<4;r4++){
      const int lrow = w*16 + g*4 + r4;
      const float mu = rs[r4] * (1.f/ENC);
      const float var = rq[r4] * (1.f/ENC) - mu*mu;
      mus[lrow] = mu;
      rss[lrow] = rsqrtf(var + EPSV);
    }
  }
  __syncthreads();
  float gv[12], bv[12];
  #pragma unroll
  for(int j2=0;j2<12;j2++){ gv[j2] = gn[lane + j2*64]; bv[j2] = bn[lane + j2*64]; }
  for(int r=0; r<16; ++r){
    const int lrow = w*16 + r;
    const float mu = mus[lrow], rstd = rss[lrow];
    float* orow = out + (size_t)(mb+lrow)*ENC;
    #pragma unroll
    for(int j2=0;j2<12;j2++){
      const float y = bf2f(Ys[lrow*YSTR + lane + j2*64]);
      orow[lane + j2*64] = (y - mu)*rstd*gv[j2] + bv[j2];
    }
  }
}

extern "C" void kernel_launch(void* const* d_in, const int* in_sizes, int n_in,
                              void* d_out, int out_size, void* d_ws, size_t ws_size,
                              hipStream_t stream) {
  const float* x    = (const float*)d_in[0];
  const int*   ei   = (const int*)  d_in[1];
  const float* Wfc  = (const float*)d_in[2];
  const float* bfc  = (const float*)d_in[3];
  const float* W1l  = (const float*)d_in[4];
  const float* b1l  = (const float*)d_in[5];
  const float* W1r  = (const float*)d_in[6];
  const float* b1r  = (const float*)d_in[7];
  const float* att1 = (const float*)d_in[8];
  const float* bias1= (const float*)d_in[9];
  const float* g1   = (const float*)d_in[10];
  const float* bb1  = (const float*)d_in[11];
  const float* W2l  = (const float*)d_in[12];
  const float* b2l  = (const float*)d_in[13];
  const float* W2r  = (const float*)d_in[14];
  const float* b2r  = (const float*)d_in[15];
  const float* att2 = (const float*)d_in[16];
  const float* bias2= (const float*)d_in[17];
  const float* gn   = (const float*)d_in[18];
  const float* bn   = (const float*)d_in[19];
  float* out = (float*)d_out;

  char* w = (char*)d_ws;
  auto alloc = [&](size_t bytes){ void* p = (void*)w; w += (bytes + 255) & ~(size_t)255; return p; };
  int*      hist     = (int*)     alloc((size_t)N_NODES*4);   // contiguous with cursor
  int*      cursor   = (int*)     alloc((size_t)N_NODES*4);
  int*      rowstart = (int*)     alloc((size_t)(N_NODES+1)*4);
  int*      ssrc     = (int*)     alloc((size_t)EP*4);
  unsigned* xl1u     = (unsigned*)alloc((size_t)N_NODES*64*4);
  unsigned* xr1u     = (unsigned*)alloc((size_t)N_NODES*64*4);
  float*    dotl1    = (float*)   alloc((size_t)N_NODES*4);
  float*    dotr1    = (float*)   alloc((size_t)N_NODES*4);
  float*    dotl2    = (float*)   alloc((size_t)N_NODES*4);
  float*    dotr2    = (float*)   alloc((size_t)N_NODES*4);
  unsigned* h1u      = (unsigned*)alloc((size_t)N_NODES*64*4);
  unsigned* aggb     = (unsigned*)alloc((size_t)N_NODES*64*4);
  u8*       xl8      = (u8*)      alloc((size_t)N_NODES*ENC);
  u16*      xr2u     = (u16*)     alloc((size_t)N_NODES*ENC*2);
  u16*      Wtb      = (u16*)     alloc((size_t)2*ENC*HID*2);
  float*    w2a      = (float*)   alloc((size_t)W2A_BLKS*4);

  hipMemsetAsync(hist, 0, (size_t)N_NODES*8, stream);   // hist + cursor

  prep_kernel<<<LIN1_BLKS+WPREP_BLKS+HIST_BLKS+W2A_BLKS, 256, 0, stream>>>(
      x, W1l, b1l, W1r, b1r, att1, W2l, W2r, b2l, b2r, att2, ei,
      xl1u, xr1u, dotl1, dotr1, Wtb, w2a, hist);
  scan_kernel<<<1, 1024, 0, stream>>>(hist, rowstart);
  scatter_kernel<<<EP/256, 256, 0, stream>>>(ei, rowstart, cursor, ssrc);
  node1_kernel<<<N_NODES/4, 256, 0, stream>>>(xl1u, xr1u, att1, dotl1, dotr1,
                                              bias1, g1, bb1, w2a,
                                              rowstart, ssrc, h1u, dotl2, dotr2);
  mfma_lin2_kernel<<<dim3(N_NODES/LBM, 2*ENC/LBN), 256, 0, stream>>>(
      (const u16*)h1u, Wtb, b2l, b2r, xl8, xr2u);
  node2b_kernel<<<N_NODES/4, 256, 0, stream>>>(xl8, (const u8*)xr2u, att2,
                                               dotl2, dotr2, h1u,
                                               rowstart, ssrc, aggb);
  gemm3_mfma_kernel<<<N_NODES/64, 256, 0, stream>>>((const u16*)aggb, Wtb, b2l, bias2,
                                                    x, Wfc, bfc, gn, bn, out);
}

// Round 15
// 186.221 us; speedup vs baseline: 1.0874x; 1.0109x over previous
//
#include <hip/hip_runtime.h>

#define N_NODES 16384
#define N_EDGES 262144
#define EP (N_EDGES + N_NODES)   // with self-loops
#define HID 128
#define ENC 768
#define EPSV 1e-5f

typedef unsigned short u16;
typedef unsigned char u8;
using f32x4  = __attribute__((ext_vector_type(4))) float;
using bf16x8 = __attribute__((ext_vector_type(8))) short;
using v2f    = __attribute__((ext_vector_type(2))) float;

__device__ __forceinline__ float wave_sum(float v){
  #pragma unroll
  for(int m=32;m>=1;m>>=1) v += __shfl_xor(v, m, 64);
  return v;
}
__device__ __forceinline__ unsigned bf16rtne(float f){
  const unsigned u = __float_as_uint(f);
  return (u + 0x7fffu + ((u>>16)&1u)) >> 16;
}
__device__ __forceinline__ unsigned pack2(float a, float b){
  return bf16rtne(a) | (bf16rtne(b) << 16);
}
__device__ __forceinline__ float bf2f(u16 h){ return __uint_as_float(((unsigned)h) << 16); }
__device__ __forceinline__ float plo(unsigned u){ return __uint_as_float(u << 16); }
__device__ __forceinline__ float phi(unsigned u){ return __uint_as_float(u & 0xffff0000u); }
__device__ __forceinline__ u8 f2fp8(float v){
  return (u8)(__builtin_amdgcn_cvt_pk_fp8_f32(v, v, 0, false) & 0xff);
}

// 4 fp8 channels (one dword) against sg/xr registers j..j+3
#define QD(ax, j, q) { \
  const v2f f01 = __builtin_amdgcn_cvt_pk_f32_fp8(ax, false); \
  const v2f f23 = __builtin_amdgcn_cvt_pk_f32_fp8(ax, true);  \
  q = fmaf(sg[j],   __builtin_fabsf(f01.x+xr[j]),   q); \
  q = fmaf(sg[j+1], __builtin_fabsf(f01.y+xr[j+1]), q); \
  q = fmaf(sg[j+2], __builtin_fabsf(f23.x+xr[j+2]), q); \
  q = fmaf(sg[j+3], __builtin_fabsf(f23.y+xr[j+3]), q); }

// ---- merged prep: lin1 (channel-ordered pairs, +att1 dots), Wtb, hist, W2@att2 ----
#define LIN1_BLKS (N_NODES/4)            // 4096 (one wave per node)
#define WPREP_BLKS (2*ENC*HID/256)       // 768
#define HIST_BLKS (EP/256)               // 1088
#define W2A_BLKS 258                     // 128 l + 128 r + cl + cr
__global__ __launch_bounds__(256) void prep_kernel(
    const float* __restrict__ x,
    const float* __restrict__ W1l, const float* __restrict__ b1l,
    const float* __restrict__ W1r, const float* __restrict__ b1r,
    const float* __restrict__ att1,
    const float* __restrict__ W2l, const float* __restrict__ W2r,
    const float* __restrict__ b2l, const float* __restrict__ b2r,
    const float* __restrict__ att2,
    const int* __restrict__ ei,
    unsigned* __restrict__ xl1u, unsigned* __restrict__ xr1u,
    float* __restrict__ dotl1, float* __restrict__ dotr1,
    u16* __restrict__ Wtb, float* __restrict__ w2a,
    int* __restrict__ hist){
  const int bid = blockIdx.x;
  if(bid < LIN1_BLKS){
    const int lane = threadIdx.x & 63;
    const int n = bid*4 + (threadIdx.x >> 6);
    const float x0 = x[n*3], x1 = x[n*3+1], x2 = x[n*3+2];
    const int c0 = 2*lane, c1 = 2*lane + 1;     // channel-ordered pairs
    const float la = x0*W1l[c0] + x1*W1l[HID+c0] + x2*W1l[2*HID+c0] + b1l[c0];
    const float lb = x0*W1l[c1] + x1*W1l[HID+c1] + x2*W1l[2*HID+c1] + b1l[c1];
    const float ra = x0*W1r[c0] + x1*W1r[HID+c0] + x2*W1r[2*HID+c0] + b1r[c0];
    const float rb = x0*W1r[c1] + x1*W1r[HID+c1] + x2*W1r[2*HID+c1] + b1r[c1];
    const float aa = att1[c0], ab = att1[c1];
    const float dl = wave_sum(la*aa + lb*ab);
    const float dr = wave_sum(ra*aa + rb*ab);
    if(lane == 0){ dotl1[n] = 0.6f*dl; dotr1[n] = 0.6f*dr; }
    xl1u[n*64+lane] = pack2(la, lb);
    xr1u[n*64+lane] = pack2(ra, rb);
  } else if(bid < LIN1_BLKS + WPREP_BLKS){
    const int idx = (bid - LIN1_BLKS)*256 + threadIdx.x;
    const int n = idx >> 7, k = idx & 127;
    const float v = (n < ENC) ? W2l[k*ENC + n] : W2r[k*ENC + (n-ENC)];
    Wtb[idx] = (u16)bf16rtne(v);
  } else if(bid < LIN1_BLKS + WPREP_BLKS + HIST_BLKS){
    const int i = (bid - LIN1_BLKS - WPREP_BLKS)*256 + threadIdx.x;
    const int dst = (i < N_EDGES) ? ei[N_EDGES + i] : (i - N_EDGES);
    atomicAdd(&hist[dst], 1);
  } else {
    // w2a[idx]: idx<128 -> W2l@att2 row k; idx<256 -> W2r@att2; 256/257 -> att2.b2l / att2.b2r
    const int idx = bid - (LIN1_BLKS + WPREP_BLKS + HIST_BLKS);
    const float* src = (idx < 128) ? (W2l + (size_t)idx*ENC)
                     : (idx < 256) ? (W2r + (size_t)(idx-128)*ENC)
                     : (idx == 256) ? b2l : b2r;
    float partial = 0.f;
    for(int c = threadIdx.x; c < ENC; c += 256) partial += src[c]*att2[c];
    partial = wave_sum(partial);
    __shared__ float red4[4];
    if((threadIdx.x & 63) == 0) red4[threadIdx.x >> 6] = partial;
    __syncthreads();
    if(threadIdx.x == 0) w2a[idx] = red4[0]+red4[1]+red4[2]+red4[3];
  }
}

// ---- single-block exclusive scan over N=16384 (1024 thr x 16 items) ----
__global__ __launch_bounds__(1024) void scan_kernel(
    const int* __restrict__ hist, int* __restrict__ rowstart){
  __shared__ int sums[1024];
  const int t = threadIdx.x;
  const int base = t*16;
  int loc[16];
  int s = 0;
  #pragma unroll
  for(int i=0;i<16;i++){ loc[i] = s; s += hist[base+i]; }
  sums[t] = s;
  __syncthreads();
  for(int off=1; off<1024; off<<=1){
    int v = 0;
    if(t >= off) v = sums[t-off];
    __syncthreads();
    if(t >= off) sums[t] += v;
    __syncthreads();
  }
  const int prev = (t==0) ? 0 : sums[t-1];
  #pragma unroll
  for(int i=0;i<16;i++) rowstart[base+i] = prev + loc[i];
  if(t == 1023) rowstart[N_NODES] = EP;
}

// ---- CSR build: scatter src ids; hist consumed via atomicSub (no cursor) ----
__global__ __launch_bounds__(256) void scatter_kernel(
    const int* __restrict__ ei, const int* __restrict__ rowstart,
    int* __restrict__ hist, int* __restrict__ ssrc){
  const int i = blockIdx.x*256 + threadIdx.x;        // exactly EP threads
  const int src = (i < N_EDGES) ? ei[i]           : (i - N_EDGES);
  const int dst = (i < N_EDGES) ? ei[N_EDGES + i] : (i - N_EDGES);
  const int idx = atomicSub(&hist[dst], 1) - 1;
  ssrc[rowstart[dst] + idx] = src;
}

// ---- GAT layer 1: group-of-16 per edge (8 ch/lane), 8 edges/iter (2 per group) ----
__global__ __launch_bounds__(256) void node1_kernel(
    const unsigned* __restrict__ xl1u, const unsigned* __restrict__ xr1u,
    const float* __restrict__ att1,
    const float* __restrict__ dotl1, const float* __restrict__ dotr1,
    const float* __restrict__ bias1,
    const float* __restrict__ g1, const float* __restrict__ b1,
    const float* __restrict__ w2a,
    const int* __restrict__ rowstart, const int* __restrict__ ssrc,
    unsigned* __restrict__ h1u,
    float* __restrict__ dotl2, float* __restrict__ dotr2){
  const int lane = threadIdx.x & 63;
  const int n = blockIdx.x*4 + (threadIdx.x >> 6);
  const int g = lane >> 4, k = lane & 15;
  float xr[8], sa[8];
  {
    const uint4 u = *(const uint4*)(xr1u + n*64 + 4*k);
    xr[0]=plo(u.x); xr[1]=phi(u.x); xr[2]=plo(u.y); xr[3]=phi(u.y);
    xr[4]=plo(u.z); xr[5]=phi(u.z); xr[6]=plo(u.w); xr[7]=phi(u.w);
    const float4 a0 = *(const float4*)(att1 + 8*k);
    const float4 a1 = *(const float4*)(att1 + 8*k + 4);
    sa[0]=0.4f*a0.x; sa[1]=0.4f*a0.y; sa[2]=0.4f*a0.z; sa[3]=0.4f*a0.w;
    sa[4]=0.4f*a1.x; sa[5]=0.4f*a1.y; sa[6]=0.4f*a1.z; sa[7]=0.4f*a1.w;
  }
  const float ebase = dotr1[n];
  float acc[8] = {0,0,0,0,0,0,0,0};
  float denom = 0.f;
  const int p0 = rowstart[n], p1 = rowstart[n+1];
  int base = p0;
  for(; base + 8 <= p1; base += 8){
    const int iA = base + g, iB = base + 4 + g;
    const int sA = ssrc[iA], sB = ssrc[iB];
    const uint4 uA = *(const uint4*)(xl1u + sA*64 + 4*k);
    const uint4 uB = *(const uint4*)(xl1u + sB*64 + 4*k);
    const float dlA = dotl1[sA], dlB = dotl1[sB];
    float a[8], b[8];
    a[0]=plo(uA.x); a[1]=phi(uA.x); a[2]=plo(uA.y); a[3]=phi(uA.y);
    a[4]=plo(uA.z); a[5]=phi(uA.z); a[6]=plo(uA.w); a[7]=phi(uA.w);
    b[0]=plo(uB.x); b[1]=phi(uB.x); b[2]=plo(uB.y); b[3]=phi(uB.y);
    b[4]=plo(uB.z); b[5]=phi(uB.z); b[6]=plo(uB.w); b[7]=phi(uB.w);
    float qA = 0.f, qB = 0.f;
    #pragma unroll
    for(int j=0;j<8;j++){
      qA = fmaf(sa[j], __builtin_fabsf(a[j]+xr[j]), qA);
      qB = fmaf(sa[j], __builtin_fabsf(b[j]+xr[j]), qB);
    }
    #pragma unroll
    for(int m=1;m<16;m<<=1){
      qA += __shfl_xor(qA, m, 64);
      qB += __shfl_xor(qB, m, 64);
    }
    const float wA = __expf(qA + dlA + ebase);
    const float wB = __expf(qB + dlB + ebase);
    denom += wA + wB;
    #pragma unroll
    for(int j=0;j<8;j++) acc[j] = fmaf(wA, a[j], fmaf(wB, b[j], acc[j]));
  }
  for(; base < p1; base += 4){
    const int idx = base + g;
    const bool valid = idx < p1;
    const int s = ssrc[valid ? idx : (p1-1)];
    const uint4 u = *(const uint4*)(xl1u + s*64 + 4*k);
    float a[8];
    a[0]=plo(u.x); a[1]=phi(u.x); a[2]=plo(u.y); a[3]=phi(u.y);
    a[4]=plo(u.z); a[5]=phi(u.z); a[6]=plo(u.w); a[7]=phi(u.w);
    const float dlv = dotl1[s];
    float q = 0.f;
    #pragma unroll
    for(int j=0;j<8;j++) q = fmaf(sa[j], __builtin_fabsf(a[j]+xr[j]), q);
    q += __shfl_xor(q, 1, 64);
    q += __shfl_xor(q, 2, 64);
    q += __shfl_xor(q, 4, 64);
    q += __shfl_xor(q, 8, 64);
    float w = __expf(q + dlv + ebase);
    w = valid ? w : 0.f;
    denom += w;
    #pragma unroll
    for(int j=0;j<8;j++) acc[j] = fmaf(w, a[j], acc[j]);
  }
  // combine the 4 groups (lanes with equal k)
  #pragma unroll
  for(int m=16; m<64; m<<=1){
    denom += __shfl_xor(denom, m, 64);
    #pragma unroll
    for(int j=0;j<8;j++) acc[j] += __shfl_xor(acc[j], m, 64);
  }
  const float inv = 1.f/denom;
  const float4 bb0 = *(const float4*)(bias1 + 8*k);
  const float4 bb1 = *(const float4*)(bias1 + 8*k + 4);
  float y[8];
  y[0]=acc[0]*inv+bb0.x; y[1]=acc[1]*inv+bb0.y; y[2]=acc[2]*inv+bb0.z; y[3]=acc[3]*inv+bb0.w;
  y[4]=acc[4]*inv+bb1.x; y[5]=acc[5]*inv+bb1.y; y[6]=acc[6]*inv+bb1.z; y[7]=acc[7]*inv+bb1.w;
  float ls = 0.f, lq = 0.f;
  #pragma unroll
  for(int j=0;j<8;j++){ ls += y[j]; lq += y[j]*y[j]; }
  ls = wave_sum(ls); lq = wave_sum(lq);           // 4x duplicated over groups
  const float mu  = ls * (1.f/(4*HID));
  const float var = lq * (1.f/(4*HID)) - mu*mu;
  const float r = rsqrtf(var + EPSV);
  const float4 gg0 = *(const float4*)(g1 + 8*k);
  const float4 gg1 = *(const float4*)(g1 + 8*k + 4);
  const float4 ob0 = *(const float4*)(b1 + 8*k);
  const float4 ob1 = *(const float4*)(b1 + 8*k + 4);
  const float gv[8] = {gg0.x,gg0.y,gg0.z,gg0.w,gg1.x,gg1.y,gg1.z,gg1.w};
  const float bv[8] = {ob0.x,ob0.y,ob0.z,ob0.w,ob1.x,ob1.y,ob1.z,ob1.w};
  float z[8];
  #pragma unroll
  for(int j=0;j<8;j++){
    float zz = (y[j]-mu)*r*gv[j] + bv[j];
    z[j] = zz > 0.f ? zz : expm1f(zz);            // ELU(alpha=1)
  }
  float dl2 = 0.f, dr2 = 0.f;
  #pragma unroll
  for(int j=0;j<8;j++){
    dl2 = fmaf(z[j], w2a[8*k+j], dl2);
    dr2 = fmaf(z[j], w2a[128+8*k+j], dr2);
  }
  dl2 = wave_sum(dl2); dr2 = wave_sum(dr2);       // 4x duplicated
  if(lane == 0){
    dotl2[n] = 0.6f*(0.25f*dl2 + w2a[256]);
    dotr2[n] = 0.6f*(0.25f*dr2 + w2a[257]);
  }
  if(g == 0){
    uint4 o;
    o.x = pack2(z[0], z[1]); o.y = pack2(z[2], z[3]);
    o.z = pack2(z[4], z[5]); o.w = pack2(z[6], z[7]);
    *(uint4*)(h1u + n*64 + 4*k) = o;
  }
}

// ---- MFMA GEMM: l-half -> fp8 xl8 (random src gather), r-half -> bf16 xr2u ----
#define LBM 128
#define LBN 128
__global__ __launch_bounds__(256) void mfma_lin2_kernel(
    const u16* __restrict__ h1b, const u16* __restrict__ Wtb,
    const float* __restrict__ b2l, const float* __restrict__ b2r,
    u8* __restrict__ xl8, u16* __restrict__ xr2u){
  __shared__ __align__(16) u16 Cs[LBM*128];   // 32 KB bounce, swizzled rows
  const int t = threadIdx.x;
  const int mb = blockIdx.x * LBM;
  const int nb = blockIdx.y * LBN;
  const int w = t >> 6, lane = t & 63;
  const int l15 = lane & 15, g = lane >> 4;
  const int ar0 = mb + w*32 + l15, ar1 = ar0 + 16;
  bf16x8 a0[4], a1[4];
  #pragma unroll
  for(int ks=0;ks<4;ks++){
    a0[ks] = *(const bf16x8*)(h1b + (size_t)ar0*128 + ks*32 + g*8);
    a1[ks] = *(const bf16x8*)(h1b + (size_t)ar1*128 + ks*32 + g*8);
  }
  f32x4 acc0[8], acc1[8];
  #pragma unroll
  for(int j=0;j<8;j++){ acc0[j]=(f32x4){0,0,0,0}; acc1[j]=(f32x4){0,0,0,0}; }
  #pragma unroll
  for(int j=0;j<8;j++){
    const int brn = nb + j*16 + l15;
    #pragma unroll
    for(int ks=0;ks<4;ks++){
      const bf16x8 b = *(const bf16x8*)(Wtb + (size_t)brn*128 + ks*32 + g*8);
      acc0[j] = __builtin_amdgcn_mfma_f32_16x16x32_bf16(a0[ks], b, acc0[j], 0,0,0);
      acc1[j] = __builtin_amdgcn_mfma_f32_16x16x32_bf16(a1[ks], b, acc1[j], 0,0,0);
    }
  }
  if(nb < ENC){
    // fp8 epilogue (src score table)
    u8* Cs8 = (u8*)Cs;
    float biasj[8];
    #pragma unroll
    for(int j=0;j<8;j++) biasj[j] = b2l[nb + j*16 + l15];
    #pragma unroll
    for(int j=0;j<8;j++){
      const int col = j*16 + l15;
      #pragma unroll
      for(int r4=0;r4<4;r4++){
        const int row0 = w*32 + g*4 + r4;         // C/D: col=lane&15, row=(lane>>4)*4+reg
        Cs8[row0*128 + (col ^ ((row0&7)<<4))] = f2fp8(acc0[j][r4] + biasj[j]);
        const int row1 = row0 + 16;
        Cs8[row1*128 + (col ^ ((row1&7)<<4))] = f2fp8(acc1[j][r4] + biasj[j]);
      }
    }
    __syncthreads();
    #pragma unroll
    for(int idx=t; idx<LBM*8; idx+=256){
      const int row = idx >> 3, ch = idx & 7;
      const uint4 v = *(const uint4*)(Cs8 + row*128 + ((ch*16) ^ ((row&7)<<4)));
      *(uint4*)(xl8 + (size_t)(mb+row)*ENC + nb + ch*16) = v;
    }
  } else {
    // bf16 epilogue (dst score table — loop-invariant per node in node2b)
    const float* bsrc = b2r + (nb - ENC);
    float biasj[8];
    #pragma unroll
    for(int j=0;j<8;j++) biasj[j] = bsrc[j*16 + l15];
    #pragma unroll
    for(int j=0;j<8;j++){
      const int coll = j*16 + l15;
      #pragma unroll
      for(int r4=0;r4<4;r4++){
        const int row0 = w*32 + g*4 + r4;
        *(u16*)((char*)Cs + row0*256 + ((coll*2) ^ ((row0&7)<<4))) =
            (u16)bf16rtne(acc0[j][r4] + biasj[j]);
        const int row1 = row0 + 16;
        *(u16*)((char*)Cs + row1*256 + ((coll*2) ^ ((row1&7)<<4))) =
            (u16)bf16rtne(acc1[j][r4] + biasj[j]);
      }
    }
    __syncthreads();
    u16* dst0 = xr2u + (nb - ENC);
    const int rr = t >> 4, cc = t & 15;
    #pragma unroll
    for(int it=0; it<8; ++it){
      const int row = it*16 + rr;
      const uint4 v = *(const uint4*)((const char*)Cs + row*256 + ((cc*16) ^ ((row&7)<<4)));
      *(uint4*)(dst0 + (size_t)(mb+row)*ENC + cc*8) = v;
    }
  }
}

// ---- GAT layer 2: channel-parallel (12 fp8 ch/lane, uint3 row read),
//      8-edge unroll for deep MLP; 1 wave per node; canonical h1u ----
__global__ __launch_bounds__(256) void node2b_kernel(
    const u8* __restrict__ xl8, const u8* __restrict__ xr2u8,
    const float* __restrict__ att2,
    const float* __restrict__ dotl2, const float* __restrict__ dotr2,
    const unsigned* __restrict__ h1u,
    const int* __restrict__ rowstart, const int* __restrict__ ssrc,
    unsigned* __restrict__ aggb){
  const int lane = threadIdx.x & 63;
  const int n = blockIdx.x*4 + (threadIdx.x >> 6);
  // loop-invariant: this lane's 12 channels of 0.4*att2 and xr2[n]
  float sg[12], xr[12];
  {
    const float4* A4 = (const float4*)(att2 + lane*12);   // 48B stride, 16-aligned
    const float4 s0 = A4[0], s1 = A4[1], s2 = A4[2];
    sg[0]=0.4f*s0.x; sg[1]=0.4f*s0.y; sg[2]=0.4f*s0.z; sg[3]=0.4f*s0.w;
    sg[4]=0.4f*s1.x; sg[5]=0.4f*s1.y; sg[6]=0.4f*s1.z; sg[7]=0.4f*s1.w;
    sg[8]=0.4f*s2.x; sg[9]=0.4f*s2.y; sg[10]=0.4f*s2.z; sg[11]=0.4f*s2.w;
    const u8* xrrow = xr2u8 + (size_t)n*(ENC*2) + lane*24;
    const uint2 r0 = *(const uint2*)(xrrow);
    const uint2 r1 = *(const uint2*)(xrrow + 8);
    const uint2 r2 = *(const uint2*)(xrrow + 16);
    xr[0]=plo(r0.x); xr[1]=phi(r0.x); xr[2]=plo(r0.y); xr[3]=phi(r0.y);
    xr[4]=plo(r1.x); xr[5]=phi(r1.x); xr[6]=plo(r1.y); xr[7]=phi(r1.y);
    xr[8]=plo(r2.x); xr[9]=phi(r2.x); xr[10]=plo(r2.y); xr[11]=phi(r2.y);
  }
  const float ebase = dotr2[n];
  float denom = 0.f, acc0 = 0.f, acc1 = 0.f;
  int p = rowstart[n];
  const int p1 = rowstart[n+1];
  for(; p+7 < p1; p += 8){
    int s[8];
    #pragma unroll
    for(int e=0;e<8;e++) s[e] = ssrc[p+e];
    uint3 a[8]; unsigned h[8]; float dl[8];
    #pragma unroll
    for(int e=0;e<8;e++){
      a[e]  = *(const uint3*)(xl8 + (size_t)s[e]*ENC + lane*12);
      h[e]  = h1u[s[e]*64 + lane];
      dl[e] = dotl2[s[e]];
    }
    float q[8];
    #pragma unroll
    for(int e=0;e<8;e++){
      q[e] = 0.f;
      QD(a[e].x, 0, q[e]) QD(a[e].y, 4, q[e]) QD(a[e].z, 8, q[e])
    }
    #pragma unroll
    for(int m=32;m>=1;m>>=1){
      #pragma unroll
      for(int e=0;e<8;e++) q[e] += __shfl_xor(q[e], m, 64);
    }
    #pragma unroll
    for(int e=0;e<8;e++){
      const float w = __expf(q[e] + dl[e] + ebase);
      denom += w;
      acc0 += w*plo(h[e]);
      acc1 += w*phi(h[e]);
    }
  }
  for(; p < p1; ++p){
    const int s0 = ssrc[p];
    const uint3 a0 = *(const uint3*)(xl8 + (size_t)s0*ENC + lane*12);
    float q0 = 0.f;
    QD(a0.x, 0, q0) QD(a0.y, 4, q0) QD(a0.z, 8, q0)
    const unsigned h0 = h1u[s0*64 + lane];
    const float w0 = __expf(wave_sum(q0) + dotl2[s0] + ebase);
    denom += w0; acc0 += w0*plo(h0); acc1 += w0*phi(h0);
  }
  const float inv = 1.f/denom;
  aggb[n*64 + lane] = pack2(acc0*inv, acc1*inv);    // channels 2lane, 2lane+1
}

// ---- final fused: out = LN( aggb@W2l + b2l + bias2 + x@Wfc + bfc ) ----
#define YSTR 770
__global__ __launch_bounds__(256) void gemm3_mfma_kernel(
    const u16* __restrict__ aggb, const u16* __restrict__ Wtb,
    const float* __restrict__ b2l, const float* __restrict__ bias2,
    const float* __restrict__ x, const float* __restrict__ Wfc,
    const float* __restrict__ bfc,
    const float* __restrict__ gn, const float* __restrict__ bn,
    float* __restrict__ out){
  __shared__ u16 Ys[64*YSTR];
  __shared__ float cbs[ENC];
  __shared__ float wfs[3][ENC];
  __shared__ float mus[64], rss[64];
  const int t = threadIdx.x;
  const int mb = blockIdx.x * 64;
  for(int c=t; c<ENC; c+=256){
    cbs[c] = b2l[c] + bias2[c] + bfc[c];
    wfs[0][c] = Wfc[c]; wfs[1][c] = Wfc[ENC+c]; wfs[2][c] = Wfc[2*ENC+c];
  }
  const int w = t >> 6, lane = t & 63;
  const int l15 = lane & 15, g = lane >> 4;
  const int ar = mb + w*16 + l15;
  bf16x8 a[4];
  #pragma unroll
  for(int ks=0;ks<4;ks++)
    a[ks] = *(const bf16x8*)(aggb + (size_t)ar*128 + ks*32 + g*8);
  float xv0[4], xv1[4], xv2[4];
  #pragma unroll
  for(int r4=0;r4<4;r4++){
    const int rrow = mb + w*16 + g*4 + r4;
    xv0[r4] = x[rrow*3]; xv1[r4] = x[rrow*3+1]; xv2[r4] = x[rrow*3+2];
  }
  float rs[4] = {0,0,0,0}, rq[4] = {0,0,0,0};
  __syncthreads();
  #pragma unroll
  for(int sub=0; sub<6; ++sub){
    const int nb = sub*128;
    f32x4 acc[8];
    #pragma unroll
    for(int j=0;j<8;j++) acc[j]=(f32x4){0,0,0,0};
    #pragma unroll
    for(int j=0;j<8;j++){
      const int brn = nb + j*16 + l15;
      #pragma unroll
      for(int ks=0;ks<4;ks++){
        const bf16x8 b = *(const bf16x8*)(Wtb + (size_t)brn*128 + ks*32 + g*8);
        acc[j] = __builtin_amdgcn_mfma_f32_16x16x32_bf16(a[ks], b, acc[j], 0,0,0);
      }
    }
    #pragma unroll
    for(int j=0;j<8;j++){
      const int col = nb + j*16 + l15;
      const float cb = cbs[col];
      const float w0 = wfs[0][col], w1 = wfs[1][col], w2 = wfs[2][col];
      #pragma unroll
      for(int r4=0;r4<4;r4++){
        const int lrow = w*16 + g*4 + r4;
        const float y = acc[j][r4] + cb + xv0[r4]*w0 + xv1[r4]*w1 + xv2[r4]*w2;
        rs[r4] += y; rq[r4] += y*y;
        Ys[lrow*YSTR + col] = (u16)bf16rtne(y);
      }
    }
  }
  #pragma unroll
  for(int m=8;m>=1;m>>=1){
    #pragma unroll
    for(int r4=0;r4<4;r4++){
      rs[r4] += __shfl_xor(rs[r4], m, 64);
      rq[r4] += __shfl_xor(rq[r4], m, 64);
    }
  }
  if(l15 == 0){
    #pragma unroll
    for(int r4=0;r4<4;r4++){
      const int lrow = w*16 + g*4 + r4;
      const float mu = rs[r4] * (1.f/ENC);
      const float var = rq[r4] * (1.f/ENC) - mu*mu;
      mus[lrow] = mu;
      rss[lrow] = rsqrtf(var + EPSV);
    }
  }
  __syncthreads();
  float gv[12], bv[12];
  #pragma unroll
  for(int j2=0;j2<12;j2++){ gv[j2] = gn[lane + j2*64]; bv[j2] = bn[lane + j2*64]; }
  for(int r=0; r<16; ++r){
    const int lrow = w*16 + r;
    const float mu = mus[lrow], rstd = rss[lrow];
    float* orow = out + (size_t)(mb+lrow)*ENC;
    #pragma unroll
    for(int j2=0;j2<12;j2++){
      const float y = bf2f(Ys[lrow*YSTR + lane + j2*64]);
      orow[lane + j2*64] = (y - mu)*rstd*gv[j2] + bv[j2];
    }
  }
}

extern "C" void kernel_launch(void* const* d_in, const int* in_sizes, int n_in,
                              void* d_out, int out_size, void* d_ws, size_t ws_size,
                              hipStream_t stream) {
  const float* x    = (const float*)d_in[0];
  const int*   ei   = (const int*)  d_in[1];
  const float* Wfc  = (const float*)d_in[2];
  const float* bfc  = (const float*)d_in[3];
  const float* W1l  = (const float*)d_in[4];
  const float* b1l  = (const float*)d_in[5];
  const float* W1r  = (const float*)d_in[6];
  const float* b1r  = (const float*)d_in[7];
  const float* att1 = (const float*)d_in[8];
  const float* bias1= (const float*)d_in[9];
  const float* g1   = (const float*)d_in[10];
  const float* bb1  = (const float*)d_in[11];
  const float* W2l  = (const float*)d_in[12];
  const float* b2l  = (const float*)d_in[13];
  const float* W2r  = (const float*)d_in[14];
  const float* b2r  = (const float*)d_in[15];
  const float* att2 = (const float*)d_in[16];
  const float* bias2= (const float*)d_in[17];
  const float* gn   = (const float*)d_in[18];
  const float* bn   = (const float*)d_in[19];
  float* out = (float*)d_out;

  char* w = (char*)d_ws;
  auto alloc = [&](size_t bytes){ void* p = (void*)w; w += (bytes + 255) & ~(size_t)255; return p; };
  int*      hist     = (int*)     alloc((size_t)N_NODES*4);
  int*      rowstart = (int*)     alloc((size_t)(N_NODES+1)*4);
  int*      ssrc     = (int*)     alloc((size_t)EP*4);
  unsigned* xl1u     = (unsigned*)alloc((size_t)N_NODES*64*4);
  unsigned* xr1u     = (unsigned*)alloc((size_t)N_NODES*64*4);
  float*    dotl1    = (float*)   alloc((size_t)N_NODES*4);
  float*    dotr1    = (float*)   alloc((size_t)N_NODES*4);
  float*    dotl2    = (float*)   alloc((size_t)N_NODES*4);
  float*    dotr2    = (float*)   alloc((size_t)N_NODES*4);
  unsigned* h1u      = (unsigned*)alloc((size_t)N_NODES*64*4);
  unsigned* aggb     = (unsigned*)alloc((size_t)N_NODES*64*4);
  u8*       xl8      = (u8*)      alloc((size_t)N_NODES*ENC);
  u16*      xr2u     = (u16*)     alloc((size_t)N_NODES*ENC*2);
  u16*      Wtb      = (u16*)     alloc((size_t)2*ENC*HID*2);
  float*    w2a      = (float*)   alloc((size_t)W2A_BLKS*4);

  hipMemsetAsync(hist, 0, (size_t)N_NODES*4, stream);

  prep_kernel<<<LIN1_BLKS+WPREP_BLKS+HIST_BLKS+W2A_BLKS, 256, 0, stream>>>(
      x, W1l, b1l, W1r, b1r, att1, W2l, W2r, b2l, b2r, att2, ei,
      xl1u, xr1u, dotl1, dotr1, Wtb, w2a, hist);
  scan_kernel<<<1, 1024, 0, stream>>>(hist, rowstart);
  scatter_kernel<<<EP/256, 256, 0, stream>>>(ei, rowstart, hist, ssrc);
  node1_kernel<<<N_NODES/4, 256, 0, stream>>>(xl1u, xr1u, att1, dotl1, dotr1,
                                              bias1, g1, bb1, w2a,
                                              rowstart, ssrc, h1u, dotl2, dotr2);
  mfma_lin2_kernel<<<dim3(N_NODES/LBM, 2*ENC/LBN), 256, 0, stream>>>(
      (const u16*)h1u, Wtb, b2l, b2r, xl8, xr2u);
  node2b_kernel<<<N_NODES/4, 256, 0, stream>>>(xl8, (const u8*)xr2u, att2,
                                               dotl2, dotr2, h1u,
                                               rowstart, ssrc, aggb);
  gemm3_mfma_kernel<<<N_NODES/64, 256, 0, stream>>>((const u16*)aggb, Wtb, b2l, bias2,
                                                    x, Wfc, bfc, gn, bn, out);
}